// Round 8
// baseline (403.775 us; speedup 1.0000x reference)
//
#include <hip/hip_runtime.h>
#include <hip/hip_bf16.h>

#define N_NODES 100000
#define NUM_APS 1000
#define IN_F 32
#define HID 64
#define SCAN_BLKS ((N_NODES + 255) / 256)  // 391
#define MASK40 ((1ull << 40) - 1)

typedef __hip_bfloat16 bf16;
typedef unsigned long long ull;

__device__ __forceinline__ float b2f(bf16 v) { return __bfloat162float(v); }
__device__ __forceinline__ float blo(unsigned u) { return __uint_as_float(u << 16); }
__device__ __forceinline__ float bhi(unsigned u) { return __uint_as_float(u & 0xffff0000u); }
__device__ __forceinline__ unsigned packbf(float x, float y) {
    bf16 a = __float2bfloat16(x), b = __float2bfloat16(y);
    unsigned short ua = *reinterpret_cast<unsigned short*>(&a);
    unsigned short ub = *reinterpret_cast<unsigned short*>(&b);
    return (unsigned)ua | ((unsigned)ub << 16);
}
// 4B edge record: r<<15 | q15(ew)
__device__ __forceinline__ unsigned rec_r(unsigned v) { return v >> 15; }
__device__ __forceinline__ float rec_w(unsigned v) { return (v & 32767u) * (1.f / 32768.f); }

// ---------- CSR build ----------
// One packed 64-bit atomic per edge (verified round 7): high 24 bits count,
// low 40 bits sum of ew in 2^-24 fixed point.
__global__ void cntdeg_pack_k(const int* __restrict__ col, const float* __restrict__ ew,
                              ull* __restrict__ packed, int E) {
    int e = blockIdx.x * blockDim.x + threadIdx.x;
    if (e < E) {
        ull add = (1ull << 40) | (ull)(ew[e] * 16777216.0f);
        atomicAdd(&packed[col[e]], add);
    }
}

__global__ void dinv_k(const ull* __restrict__ packed, float* __restrict__ dinv, int n) {
    int i = blockIdx.x * blockDim.x + threadIdx.x;
    if (i >= n) return;
    float deg = (float)(packed[i] & MASK40) * (1.0f / 16777216.0f);
    dinv[i] = deg > 0.f ? 1.0f / sqrtf(deg) : 0.f;
}

// inclusive scan of counts (read from packed) within 256-blocks
__global__ __launch_bounds__(256) void scan1p_k(const ull* __restrict__ packed,
                                                int* __restrict__ off, int* __restrict__ bsum) {
    __shared__ int s[256];
    int i = blockIdx.x * 256 + threadIdx.x;
    int v = (i < N_NODES) ? (int)(packed[i] >> 40) : 0;
    s[threadIdx.x] = v;
    __syncthreads();
    for (int d = 1; d < 256; d <<= 1) {
        int t = (threadIdx.x >= d) ? s[threadIdx.x - d] : 0;
        __syncthreads();
        s[threadIdx.x] += t;
        __syncthreads();
    }
    if (i < N_NODES) off[i] = s[threadIdx.x];
    if (threadIdx.x == 255) bsum[blockIdx.x] = s[255];
}

// exclusive scan of the 391 block sums (verbatim, verified)
__global__ __launch_bounds__(512) void scan2_k(int* __restrict__ bsum) {
    __shared__ int s[512];
    int v = (threadIdx.x < SCAN_BLKS) ? bsum[threadIdx.x] : 0;
    s[threadIdx.x] = v;
    __syncthreads();
    for (int d = 1; d < 512; d <<= 1) {
        int t = (threadIdx.x >= d) ? s[threadIdx.x - d] : 0;
        __syncthreads();
        s[threadIdx.x] += t;
        __syncthreads();
    }
    if (threadIdx.x < SCAN_BLKS) bsum[threadIdx.x] = s[threadIdx.x] - v;
}

// to global exclusive offsets
__global__ void scan3p_k(const ull* __restrict__ packed, int* __restrict__ off,
                         const int* __restrict__ bsum) {
    int i = blockIdx.x * 256 + threadIdx.x;
    if (i < N_NODES) off[i] = off[i] - (int)(packed[i] >> 40) + bsum[blockIdx.x];
}

// scatter 4B records (r<<15|q15) into CSR order; off[] becomes segment ENDS.
// No dinv dependency (raw ew stored).
__global__ void scatter4_k(const int* __restrict__ row, const int* __restrict__ col,
                           const float* __restrict__ ew, int* __restrict__ off,
                           unsigned* __restrict__ ed, int E) {
    int e = blockIdx.x * blockDim.x + threadIdx.x;
    if (e >= E) return;
    int c = col[e], r = row[e];
    int pos = atomicAdd(&off[c], 1);
    unsigned q = (unsigned)(ew[e] * 32768.0f);
    if (q > 32767u) q = 32767u;
    ed[pos] = ((unsigned)r << 15) | q;
}

// xs = dinv ⊙ x, to bf16
__global__ void xs_k(const float* __restrict__ x, const float* __restrict__ dinv,
                     bf16* __restrict__ xb, int n) {
    int i = blockIdx.x * blockDim.x + threadIdx.x;
    if (i >= n) return;
    xb[i] = __float2bfloat16(x[i] * dinv[i >> 5]);
}

// ---------- gathers (unroll-4, bf16 pair lanes, 4B records) ----------
// 32-feat rows, dual out: p = d·acc (dense input), u = d²·acc (next-hop source)
__global__ __launch_bounds__(256) void gath32_dual_k(const unsigned* __restrict__ ed,
                                                     const int* __restrict__ off,
                                                     const float* __restrict__ dinv,
                                                     const unsigned* __restrict__ src,
                                                     unsigned* __restrict__ p,
                                                     unsigned* __restrict__ u, int nn) {
    int t = blockIdx.x * 256 + threadIdx.x;
    int n = t >> 4;
    if (n >= nn) return;
    int fp = t & 15;
    int s = (n == 0) ? 0 : off[n - 1];
    int e = off[n];
    float a0 = 0.f, a1 = 0.f, b0 = 0.f, b1 = 0.f;
    int i = s;
    for (; i + 4 <= e; i += 4) {
        unsigned v0 = ed[i], v1 = ed[i + 1], v2 = ed[i + 2], v3 = ed[i + 3];
        unsigned s0 = src[rec_r(v0) * 16 + fp];
        unsigned s1 = src[rec_r(v1) * 16 + fp];
        unsigned s2 = src[rec_r(v2) * 16 + fp];
        unsigned s3 = src[rec_r(v3) * 16 + fp];
        float w0 = rec_w(v0), w1 = rec_w(v1), w2 = rec_w(v2), w3 = rec_w(v3);
        a0 += w0 * blo(s0); a1 += w0 * bhi(s0);
        b0 += w1 * blo(s1); b1 += w1 * bhi(s1);
        a0 += w2 * blo(s2); a1 += w2 * bhi(s2);
        b0 += w3 * blo(s3); b1 += w3 * bhi(s3);
    }
    for (; i < e; ++i) {
        unsigned v = ed[i];
        unsigned sv = src[rec_r(v) * 16 + fp];
        float w = rec_w(v);
        a0 += w * blo(sv); a1 += w * bhi(sv);
    }
    a0 += b0; a1 += b1;
    float d = dinv[n], d2 = d * d;
    p[n * 16 + fp] = packbf(d * a0, d * a1);
    u[n * 16 + fp] = packbf(d2 * a0, d2 * a1);
}

// 32-feat rows, single out p = d·acc
__global__ __launch_bounds__(256) void gath32_one_k(const unsigned* __restrict__ ed,
                                                    const int* __restrict__ off,
                                                    const float* __restrict__ dinv,
                                                    const unsigned* __restrict__ src,
                                                    unsigned* __restrict__ p, int nn) {
    int t = blockIdx.x * 256 + threadIdx.x;
    int n = t >> 4;
    if (n >= nn) return;
    int fp = t & 15;
    int s = (n == 0) ? 0 : off[n - 1];
    int e = off[n];
    float a0 = 0.f, a1 = 0.f, b0 = 0.f, b1 = 0.f;
    int i = s;
    for (; i + 4 <= e; i += 4) {
        unsigned v0 = ed[i], v1 = ed[i + 1], v2 = ed[i + 2], v3 = ed[i + 3];
        unsigned s0 = src[rec_r(v0) * 16 + fp];
        unsigned s1 = src[rec_r(v1) * 16 + fp];
        unsigned s2 = src[rec_r(v2) * 16 + fp];
        unsigned s3 = src[rec_r(v3) * 16 + fp];
        float w0 = rec_w(v0), w1 = rec_w(v1), w2 = rec_w(v2), w3 = rec_w(v3);
        a0 += w0 * blo(s0); a1 += w0 * bhi(s0);
        b0 += w1 * blo(s1); b1 += w1 * bhi(s1);
        a0 += w2 * blo(s2); a1 += w2 * bhi(s2);
        b0 += w3 * blo(s3); b1 += w3 * bhi(s3);
    }
    for (; i < e; ++i) {
        unsigned v = ed[i];
        unsigned sv = src[rec_r(v) * 16 + fp];
        float w = rec_w(v);
        a0 += w * blo(sv); a1 += w * bhi(sv);
    }
    a0 += b0; a1 += b1;
    float d = dinv[n];
    p[n * 16 + fp] = packbf(d * a0, d * a1);
}

// 64-feat rows: u = d²·acc always; q = d·acc for n < qmax
__global__ __launch_bounds__(256) void gath64_dual_k(const unsigned* __restrict__ ed,
                                                     const int* __restrict__ off,
                                                     const float* __restrict__ dinv,
                                                     const unsigned* __restrict__ src,
                                                     unsigned* __restrict__ u,
                                                     unsigned* __restrict__ q, int nn,
                                                     int qmax) {
    int t = blockIdx.x * 256 + threadIdx.x;
    int n = t >> 5;
    if (n >= nn) return;
    int fp = t & 31;
    int s = (n == 0) ? 0 : off[n - 1];
    int e = off[n];
    float a0 = 0.f, a1 = 0.f, b0 = 0.f, b1 = 0.f;
    int i = s;
    for (; i + 4 <= e; i += 4) {
        unsigned v0 = ed[i], v1 = ed[i + 1], v2 = ed[i + 2], v3 = ed[i + 3];
        unsigned s0 = src[rec_r(v0) * 32 + fp];
        unsigned s1 = src[rec_r(v1) * 32 + fp];
        unsigned s2 = src[rec_r(v2) * 32 + fp];
        unsigned s3 = src[rec_r(v3) * 32 + fp];
        float w0 = rec_w(v0), w1 = rec_w(v1), w2 = rec_w(v2), w3 = rec_w(v3);
        a0 += w0 * blo(s0); a1 += w0 * bhi(s0);
        b0 += w1 * blo(s1); b1 += w1 * bhi(s1);
        a0 += w2 * blo(s2); a1 += w2 * bhi(s2);
        b0 += w3 * blo(s3); b1 += w3 * bhi(s3);
    }
    for (; i < e; ++i) {
        unsigned v = ed[i];
        unsigned sv = src[rec_r(v) * 32 + fp];
        float w = rec_w(v);
        a0 += w * blo(sv); a1 += w * bhi(sv);
    }
    a0 += b0; a1 += b1;
    float d = dinv[n], d2 = d * d;
    u[n * 32 + fp] = packbf(d2 * a0, d2 * a1);
    if (n < qmax) q[n * 32 + fp] = packbf(d * a0, d * a1);
}

// 64-feat rows, nn nodes only, single out q = d·acc
__global__ __launch_bounds__(256) void gath64_one_k(const unsigned* __restrict__ ed,
                                                    const int* __restrict__ off,
                                                    const float* __restrict__ dinv,
                                                    const unsigned* __restrict__ src,
                                                    unsigned* __restrict__ q, int nn) {
    int t = blockIdx.x * 256 + threadIdx.x;
    int n = t >> 5;
    if (n >= nn) return;
    int fp = t & 31;
    int s = (n == 0) ? 0 : off[n - 1];
    int e = off[n];
    float a0 = 0.f, a1 = 0.f, b0 = 0.f, b1 = 0.f;
    int i = s;
    for (; i + 4 <= e; i += 4) {
        unsigned v0 = ed[i], v1 = ed[i + 1], v2 = ed[i + 2], v3 = ed[i + 3];
        unsigned s0 = src[rec_r(v0) * 32 + fp];
        unsigned s1 = src[rec_r(v1) * 32 + fp];
        unsigned s2 = src[rec_r(v2) * 32 + fp];
        unsigned s3 = src[rec_r(v3) * 32 + fp];
        float w0 = rec_w(v0), w1 = rec_w(v1), w2 = rec_w(v2), w3 = rec_w(v3);
        a0 += w0 * blo(s0); a1 += w0 * bhi(s0);
        b0 += w1 * blo(s1); b1 += w1 * bhi(s1);
        a0 += w2 * blo(s2); a1 += w2 * bhi(s2);
        b0 += w3 * blo(s3); b1 += w3 * bhi(s3);
    }
    for (; i < e; ++i) {
        unsigned v = ed[i];
        unsigned sv = src[rec_r(v) * 32 + fp];
        float w = rec_w(v);
        a0 += w * blo(sv); a1 += w * bhi(sv);
    }
    a0 += b0; a1 += b1;
    float d = dinv[n];
    q[n * 32 + fp] = packbf(d * a0, d * a1);
}

// ---------- dense layers ----------
// h = lrelu(x@w0 + p1@w1 + p2@w2 + b); h1s = dinv⊙h (all), h1p = h (n<NUM_APS)
__global__ __launch_bounds__(256) void dense1b_k(const float* __restrict__ x,
                                                 const bf16* __restrict__ p1,
                                                 const bf16* __restrict__ p2,
                                                 const float* __restrict__ w,
                                                 const float* __restrict__ b,
                                                 const float* __restrict__ dinv,
                                                 bf16* __restrict__ h1s,
                                                 bf16* __restrict__ h1p) {
    __shared__ float sw[3 * IN_F * HID];  // 24 KB
    __shared__ float sx[4][3 * IN_F];
    for (int i = threadIdx.x; i < 3 * IN_F * HID; i += 256) sw[i] = w[i];
    int nb = blockIdx.x * 4;
    for (int k = threadIdx.x; k < 4 * 96; k += 256) {
        int ln = k / 96, j = k % 96;
        int n = nb + ln;
        float v = 0.f;
        if (n < N_NODES) {
            int hop = j >> 5, ii = j & 31;
            if (hop == 0) v = x[n * IN_F + ii];
            else v = b2f((hop == 1 ? p1 : p2)[n * IN_F + ii]);
        }
        sx[ln][j] = v;
    }
    __syncthreads();
    int ln = threadIdx.x >> 6;
    int n = nb + ln;
    if (n >= N_NODES) return;
    int f = threadIdx.x & 63;
    float acc = b[f];
#pragma unroll 8
    for (int j = 0; j < 96; ++j) acc += sx[ln][j] * sw[j * HID + f];
    acc = acc > 0.f ? acc : 0.01f * acc;
    h1s[n * HID + f] = __float2bfloat16(acc * dinv[n]);
    if (n < NUM_APS) h1p[n * HID + f] = __float2bfloat16(acc);
}

// ap = lrelu(h1p@w0 + q1@w1 + q2@w2 + b), first NUM_APS nodes, fp32 out (verbatim)
__global__ __launch_bounds__(256) void dense2_k(const bf16* __restrict__ h1p,
                                                const bf16* __restrict__ q1,
                                                const bf16* __restrict__ q2,
                                                const float* __restrict__ w,
                                                const float* __restrict__ b,
                                                float* __restrict__ ap) {
    __shared__ float sw[3 * HID * HID];  // 48 KB
    __shared__ float sx[4][3 * HID];
    for (int i = threadIdx.x; i < 3 * HID * HID; i += 256) sw[i] = w[i];
    int nb = blockIdx.x * 4;
    for (int k = threadIdx.x; k < 4 * 192; k += 256) {
        int ln = k / 192, j = k % 192;
        int n = nb + ln;
        float v = 0.f;
        if (n < NUM_APS) {
            int hop = j >> 6, ii = j & 63;
            const bf16* sp = (hop == 0) ? h1p : (hop == 1 ? q1 : q2);
            v = b2f(sp[n * HID + ii]);
        }
        sx[ln][j] = v;
    }
    __syncthreads();
    int ln = threadIdx.x >> 6;
    int n = nb + ln;
    if (n >= NUM_APS) return;
    int f = threadIdx.x & 63;
    float acc = b[f];
#pragma unroll 8
    for (int j = 0; j < 192; ++j) acc += sx[ln][j] * sw[j * HID + f];
    acc = acc > 0.f ? acc : 0.01f * acc;
    ap[n * HID + f] = acc;
}

// two 64->3 heads (verbatim)
__global__ void logits_k(const float* __restrict__ ap,
                         const float* __restrict__ wch, const float* __restrict__ bch,
                         const float* __restrict__ wpw, const float* __restrict__ bpw,
                         float* __restrict__ out) {
    int idx = blockIdx.x * blockDim.x + threadIdx.x;
    if (idx >= NUM_APS * 6) return;
    int n = idx / 6, j = idx % 6;
    const float* w;
    float bb;
    float* o;
    if (j < 3) {
        w = wch + j; bb = bch[j]; o = out + n * 3 + j;
    } else {
        int jj = j - 3;
        w = wpw + jj; bb = bpw[jj]; o = out + NUM_APS * 3 + n * 3 + jj;
    }
    float acc = bb;
    const float* a = ap + n * HID;
#pragma unroll
    for (int i = 0; i < HID; ++i) acc += a[i] * w[i * 3];
    *o = acc;
}

extern "C" void kernel_launch(void* const* d_in, const int* in_sizes, int n_in,
                              void* d_out, int out_size, void* d_ws, size_t ws_size,
                              hipStream_t stream) {
    const float* x   = (const float*)d_in[0];
    const int*   ei  = (const int*)d_in[1];
    const float* ea  = (const float*)d_in[2];
    const float* w1  = (const float*)d_in[3];
    const float* b1  = (const float*)d_in[4];
    const float* w2  = (const float*)d_in[5];
    const float* b2  = (const float*)d_in[6];
    const float* wch = (const float*)d_in[7];
    const float* bch = (const float*)d_in[8];
    const float* wpw = (const float*)d_in[9];
    const float* bpw = (const float*)d_in[10];

    const int E = in_sizes[2];  // 1,600,000
    const int* row  = ei;
    const int* colv = ei + E;

    // ---- workspace layout (4-byte units), ~34.6 MB ----
    // ed 1.6M | packed 0.2M | off 0.1M | dinv 0.1M | bsum 512 |
    // xs 1.6M, u1 1.6M  (→ h1s 3.2M after dense1)
    // p1 1.6M, p2 1.6M  (→ u3 3.2M after gath64_dual)
    // h1p 32K | q1 32K | q2 32K | ap 64K
    float* ws = (float*)d_ws;
    unsigned* ed   = (unsigned*)ws;                 // [0, 1.6M)
    ull*    packed = (ull*)(ws + 1600000);          // [1.6M, 1.8M)
    int*    off    = (int*)(ws + 1800000);          // [1.8M, 1.9M)
    float*  dinv   = ws + 1900000;                  // [1.9M, 2.0M)
    int*    bsum   = (int*)(ws + 2000000);          // 512
    unsigned* xs   = (unsigned*)(ws + 2100000);     // [2.1M, 3.7M)
    unsigned* u1   = xs + 1600000;                  // [3.7M, 5.3M)
    unsigned* p1   = (unsigned*)(ws + 5300000);     // [5.3M, 6.9M)
    unsigned* p2   = p1 + 1600000;                  // [6.9M, 8.5M)
    unsigned* h1s  = xs;                            // 3.2M, overlays xs∪u1
    unsigned* u3   = p1;                            // 3.2M, overlays p1∪p2
    bf16*   h1p    = (bf16*)(ws + 8500000);         // 32K units
    bf16*   q1     = (bf16*)(ws + 8532000);         // 32K
    bf16*   q2     = (bf16*)(ws + 8564000);         // 32K
    float*  ap     = ws + 8596000;                  // 64K

    // ---- CSR build: packed atomic, scans from packed, 4B-record scatter ----
    hipMemsetAsync(packed, 0, (size_t)N_NODES * sizeof(ull), stream);
    cntdeg_pack_k<<<(E + 255) / 256, 256, 0, stream>>>(colv, ea, packed, E);
    dinv_k<<<SCAN_BLKS, 256, 0, stream>>>(packed, dinv, N_NODES);
    scan1p_k<<<SCAN_BLKS, 256, 0, stream>>>(packed, off, bsum);
    scan2_k<<<1, 512, 0, stream>>>(bsum);
    scan3p_k<<<SCAN_BLKS, 256, 0, stream>>>(packed, off, bsum);
    scatter4_k<<<(E + 255) / 256, 256, 0, stream>>>(row, colv, ea, off, ed, E);

    // ---- layer 1 ----
    xs_k<<<(N_NODES * IN_F + 255) / 256, 256, 0, stream>>>(x, dinv, (bf16*)xs,
                                                           N_NODES * IN_F);
    gath32_dual_k<<<(N_NODES * 16 + 255) / 256, 256, 0, stream>>>(ed, off, dinv, xs,
                                                                  p1, u1, N_NODES);
    gath32_one_k<<<(N_NODES * 16 + 255) / 256, 256, 0, stream>>>(ed, off, dinv, u1,
                                                                 p2, N_NODES);
    dense1b_k<<<(N_NODES + 3) / 4, 256, 0, stream>>>(x, (bf16*)p1, (bf16*)p2, w1, b1,
                                                     dinv, (bf16*)h1s, h1p);

    // ---- layer 2 ----
    gath64_dual_k<<<(N_NODES * 32 + 255) / 256, 256, 0, stream>>>(ed, off, dinv, h1s,
                                                                  u3, (unsigned*)q1,
                                                                  N_NODES, NUM_APS);
    gath64_one_k<<<(NUM_APS * 32 + 255) / 256, 256, 0, stream>>>(ed, off, dinv, u3,
                                                                 (unsigned*)q2, NUM_APS);
    dense2_k<<<(NUM_APS + 3) / 4, 256, 0, stream>>>(h1p, q1, q2, w2, b2, ap);

    // ---- heads ----
    logits_k<<<(NUM_APS * 6 + 255) / 256, 256, 0, stream>>>(ap, wch, bch, wpw, bpw,
                                                            (float*)d_out);
}

// Round 9
// 267.963 us; speedup vs baseline: 1.5068x; 1.5068x over previous
//
#include <hip/hip_runtime.h>
#include <hip/hip_bf16.h>

#define N_NODES 100000
#define NUM_APS 1000
#define IN_F 32
#define HID 64
#define NB 391      // bins of 256 cols: 391*256 = 100096 >= N_NODES
#define EPB 4096    // edges per block in binning passes

typedef __hip_bfloat16 bf16;
typedef unsigned long long ull;

__device__ __forceinline__ float b2f(bf16 v) { return __bfloat162float(v); }
__device__ __forceinline__ float blo(unsigned u) { return __uint_as_float(u << 16); }
__device__ __forceinline__ float bhi(unsigned u) { return __uint_as_float(u & 0xffff0000u); }
__device__ __forceinline__ unsigned packbf(float x, float y) {
    bf16 a = __float2bfloat16(x), b = __float2bfloat16(y);
    unsigned short ua = *reinterpret_cast<unsigned short*>(&a);
    unsigned short ub = *reinterpret_cast<unsigned short*>(&b);
    return (unsigned)ua | ((unsigned)ub << 16);
}
// 4B edge record: r<<15 | q15(ew)
__device__ __forceinline__ unsigned rec_r(unsigned v) { return v >> 15; }
__device__ __forceinline__ float rec_w(unsigned v) { return (v & 32767u) * (1.f / 32768.f); }

// ---------- binned CSR build ----------
// pass 1: global bin histogram (LDS-staged)
__global__ __launch_bounds__(256) void hist_k(const int* __restrict__ col,
                                              int* __restrict__ binCnt, int E) {
    __shared__ int h[NB];
    for (int i = threadIdx.x; i < NB; i += 256) h[i] = 0;
    __syncthreads();
    int e0 = blockIdx.x * EPB, e1 = min(e0 + EPB, E);
    for (int e = e0 + threadIdx.x; e < e1; e += 256) atomicAdd(&h[col[e] >> 8], 1);
    __syncthreads();
    for (int i = threadIdx.x; i < NB; i += 256) {
        int v = h[i];
        if (v) atomicAdd(&binCnt[i], v);
    }
}

// pass 2: exclusive scan of bin counts -> binBase[0..NB] (binBase[NB]=E), binPtr copy
__global__ __launch_bounds__(512) void binscan_k(const int* __restrict__ binCnt,
                                                 int* __restrict__ binBase,
                                                 int* __restrict__ binPtr) {
    __shared__ int s[512];
    int v = (threadIdx.x < NB) ? binCnt[threadIdx.x] : 0;
    s[threadIdx.x] = v;
    __syncthreads();
    for (int d = 1; d < 512; d <<= 1) {
        int t = (threadIdx.x >= d) ? s[threadIdx.x - d] : 0;
        __syncthreads();
        s[threadIdx.x] += t;
        __syncthreads();
    }
    int excl = s[threadIdx.x] - v;
    if (threadIdx.x <= NB) {
        binBase[threadIdx.x] = excl;
        if (threadIdx.x < NB) binPtr[threadIdx.x] = excl;
    }
}

// pass 3: write 8B records into bin-contiguous staging (block-local slotting ->
// each block appends ~10 consecutive records per bin tail: L2-merged writes)
__global__ __launch_bounds__(256) void binwrite_k(const int* __restrict__ row,
                                                  const int* __restrict__ col,
                                                  const float* __restrict__ ew,
                                                  int* __restrict__ binPtr,
                                                  ull* __restrict__ staging, int E) {
    __shared__ int h1[NB];
    __shared__ int base[NB];
    __shared__ int h2[NB];
    for (int i = threadIdx.x; i < NB; i += 256) { h1[i] = 0; h2[i] = 0; }
    __syncthreads();
    int e0 = blockIdx.x * EPB, e1 = min(e0 + EPB, E);
    for (int e = e0 + threadIdx.x; e < e1; e += 256) atomicAdd(&h1[col[e] >> 8], 1);
    __syncthreads();
    for (int i = threadIdx.x; i < NB; i += 256) {
        int v = h1[i];
        base[i] = v ? atomicAdd(&binPtr[i], v) : 0;
    }
    __syncthreads();
    for (int e = e0 + threadIdx.x; e < e1; e += 256) {
        int c = col[e];
        int b = c >> 8;
        int slot = atomicAdd(&h2[b], 1);
        unsigned q = (unsigned)(ew[e] * 32768.0f + 0.5f);
        if (q > 32767u) q = 32767u;
        ull rec = ((ull)(unsigned)(c & 255) << 32) |
                  (ull)(((unsigned)row[e] << 15) | q);
        staging[base[b] + slot] = rec;
    }
}

// pass 4: one block per bin. Per-col count+deg in LDS, LDS scan -> off/dinv,
// then scatter records into the bin's ~16KB ed-segment (L2-resident).
__global__ __launch_bounds__(256) void binfin_k(const ull* __restrict__ staging,
                                                const int* __restrict__ binBase,
                                                unsigned* __restrict__ ed,
                                                int* __restrict__ off,
                                                float* __restrict__ dinv) {
    __shared__ unsigned cnt[256];
    __shared__ unsigned degq[256];
    __shared__ int wptr[256];
    __shared__ unsigned s[256];
    int b = blockIdx.x;
    int e0 = binBase[b], e1 = binBase[b + 1];
    cnt[threadIdx.x] = 0;
    degq[threadIdx.x] = 0;
    __syncthreads();
    for (int i = e0 + threadIdx.x; i < e1; i += 256) {
        ull rec = staging[i];
        unsigned cl = (unsigned)(rec >> 32) & 255u;
        atomicAdd(&cnt[cl], 1u);
        atomicAdd(&degq[cl], (unsigned)rec & 32767u);
    }
    __syncthreads();
    unsigned v = cnt[threadIdx.x];
    s[threadIdx.x] = v;
    __syncthreads();
    for (int d = 1; d < 256; d <<= 1) {
        unsigned t = (threadIdx.x >= d) ? s[threadIdx.x - d] : 0;
        __syncthreads();
        s[threadIdx.x] += t;
        __syncthreads();
    }
    int colg = (b << 8) + threadIdx.x;
    if (colg < N_NODES) {
        off[colg] = e0 + (int)s[threadIdx.x];  // segment END
        float deg = (float)degq[threadIdx.x] * (1.0f / 32768.0f);
        dinv[colg] = deg > 0.f ? 1.0f / sqrtf(deg) : 0.f;
    }
    wptr[threadIdx.x] = e0 + (int)s[threadIdx.x] - (int)v;  // exclusive start
    __syncthreads();
    for (int i = e0 + threadIdx.x; i < e1; i += 256) {
        ull rec = staging[i];
        unsigned cl = (unsigned)(rec >> 32) & 255u;
        int pos = atomicAdd(&wptr[cl], 1);
        ed[pos] = (unsigned)rec;  // low 32 bits = r<<15 | q15
    }
}

// xs = dinv ⊙ x, to bf16  (verbatim round 8)
__global__ void xs_k(const float* __restrict__ x, const float* __restrict__ dinv,
                     bf16* __restrict__ xb, int n) {
    int i = blockIdx.x * blockDim.x + threadIdx.x;
    if (i >= n) return;
    xb[i] = __float2bfloat16(x[i] * dinv[i >> 5]);
}

// ---------- gathers (verbatim round 8: unroll-4, bf16 pair lanes, 4B records) ----------
__global__ __launch_bounds__(256) void gath32_dual_k(const unsigned* __restrict__ ed,
                                                     const int* __restrict__ off,
                                                     const float* __restrict__ dinv,
                                                     const unsigned* __restrict__ src,
                                                     unsigned* __restrict__ p,
                                                     unsigned* __restrict__ u, int nn) {
    int t = blockIdx.x * 256 + threadIdx.x;
    int n = t >> 4;
    if (n >= nn) return;
    int fp = t & 15;
    int s = (n == 0) ? 0 : off[n - 1];
    int e = off[n];
    float a0 = 0.f, a1 = 0.f, b0 = 0.f, b1 = 0.f;
    int i = s;
    for (; i + 4 <= e; i += 4) {
        unsigned v0 = ed[i], v1 = ed[i + 1], v2 = ed[i + 2], v3 = ed[i + 3];
        unsigned s0 = src[rec_r(v0) * 16 + fp];
        unsigned s1 = src[rec_r(v1) * 16 + fp];
        unsigned s2 = src[rec_r(v2) * 16 + fp];
        unsigned s3 = src[rec_r(v3) * 16 + fp];
        float w0 = rec_w(v0), w1 = rec_w(v1), w2 = rec_w(v2), w3 = rec_w(v3);
        a0 += w0 * blo(s0); a1 += w0 * bhi(s0);
        b0 += w1 * blo(s1); b1 += w1 * bhi(s1);
        a0 += w2 * blo(s2); a1 += w2 * bhi(s2);
        b0 += w3 * blo(s3); b1 += w3 * bhi(s3);
    }
    for (; i < e; ++i) {
        unsigned v = ed[i];
        unsigned sv = src[rec_r(v) * 16 + fp];
        float w = rec_w(v);
        a0 += w * blo(sv); a1 += w * bhi(sv);
    }
    a0 += b0; a1 += b1;
    float d = dinv[n], d2 = d * d;
    p[n * 16 + fp] = packbf(d * a0, d * a1);
    u[n * 16 + fp] = packbf(d2 * a0, d2 * a1);
}

__global__ __launch_bounds__(256) void gath32_one_k(const unsigned* __restrict__ ed,
                                                    const int* __restrict__ off,
                                                    const float* __restrict__ dinv,
                                                    const unsigned* __restrict__ src,
                                                    unsigned* __restrict__ p, int nn) {
    int t = blockIdx.x * 256 + threadIdx.x;
    int n = t >> 4;
    if (n >= nn) return;
    int fp = t & 15;
    int s = (n == 0) ? 0 : off[n - 1];
    int e = off[n];
    float a0 = 0.f, a1 = 0.f, b0 = 0.f, b1 = 0.f;
    int i = s;
    for (; i + 4 <= e; i += 4) {
        unsigned v0 = ed[i], v1 = ed[i + 1], v2 = ed[i + 2], v3 = ed[i + 3];
        unsigned s0 = src[rec_r(v0) * 16 + fp];
        unsigned s1 = src[rec_r(v1) * 16 + fp];
        unsigned s2 = src[rec_r(v2) * 16 + fp];
        unsigned s3 = src[rec_r(v3) * 16 + fp];
        float w0 = rec_w(v0), w1 = rec_w(v1), w2 = rec_w(v2), w3 = rec_w(v3);
        a0 += w0 * blo(s0); a1 += w0 * bhi(s0);
        b0 += w1 * blo(s1); b1 += w1 * bhi(s1);
        a0 += w2 * blo(s2); a1 += w2 * bhi(s2);
        b0 += w3 * blo(s3); b1 += w3 * bhi(s3);
    }
    for (; i < e; ++i) {
        unsigned v = ed[i];
        unsigned sv = src[rec_r(v) * 16 + fp];
        float w = rec_w(v);
        a0 += w * blo(sv); a1 += w * bhi(sv);
    }
    a0 += b0; a1 += b1;
    float d = dinv[n];
    p[n * 16 + fp] = packbf(d * a0, d * a1);
}

__global__ __launch_bounds__(256) void gath64_dual_k(const unsigned* __restrict__ ed,
                                                     const int* __restrict__ off,
                                                     const float* __restrict__ dinv,
                                                     const unsigned* __restrict__ src,
                                                     unsigned* __restrict__ u,
                                                     unsigned* __restrict__ q, int nn,
                                                     int qmax) {
    int t = blockIdx.x * 256 + threadIdx.x;
    int n = t >> 5;
    if (n >= nn) return;
    int fp = t & 31;
    int s = (n == 0) ? 0 : off[n - 1];
    int e = off[n];
    float a0 = 0.f, a1 = 0.f, b0 = 0.f, b1 = 0.f;
    int i = s;
    for (; i + 4 <= e; i += 4) {
        unsigned v0 = ed[i], v1 = ed[i + 1], v2 = ed[i + 2], v3 = ed[i + 3];
        unsigned s0 = src[rec_r(v0) * 32 + fp];
        unsigned s1 = src[rec_r(v1) * 32 + fp];
        unsigned s2 = src[rec_r(v2) * 32 + fp];
        unsigned s3 = src[rec_r(v3) * 32 + fp];
        float w0 = rec_w(v0), w1 = rec_w(v1), w2 = rec_w(v2), w3 = rec_w(v3);
        a0 += w0 * blo(s0); a1 += w0 * bhi(s0);
        b0 += w1 * blo(s1); b1 += w1 * bhi(s1);
        a0 += w2 * blo(s2); a1 += w2 * bhi(s2);
        b0 += w3 * blo(s3); b1 += w3 * bhi(s3);
    }
    for (; i < e; ++i) {
        unsigned v = ed[i];
        unsigned sv = src[rec_r(v) * 32 + fp];
        float w = rec_w(v);
        a0 += w * blo(sv); a1 += w * bhi(sv);
    }
    a0 += b0; a1 += b1;
    float d = dinv[n], d2 = d * d;
    u[n * 32 + fp] = packbf(d2 * a0, d2 * a1);
    if (n < qmax) q[n * 32 + fp] = packbf(d * a0, d * a1);
}

__global__ __launch_bounds__(256) void gath64_one_k(const unsigned* __restrict__ ed,
                                                    const int* __restrict__ off,
                                                    const float* __restrict__ dinv,
                                                    const unsigned* __restrict__ src,
                                                    unsigned* __restrict__ q, int nn) {
    int t = blockIdx.x * 256 + threadIdx.x;
    int n = t >> 5;
    if (n >= nn) return;
    int fp = t & 31;
    int s = (n == 0) ? 0 : off[n - 1];
    int e = off[n];
    float a0 = 0.f, a1 = 0.f, b0 = 0.f, b1 = 0.f;
    int i = s;
    for (; i + 4 <= e; i += 4) {
        unsigned v0 = ed[i], v1 = ed[i + 1], v2 = ed[i + 2], v3 = ed[i + 3];
        unsigned s0 = src[rec_r(v0) * 32 + fp];
        unsigned s1 = src[rec_r(v1) * 32 + fp];
        unsigned s2 = src[rec_r(v2) * 32 + fp];
        unsigned s3 = src[rec_r(v3) * 32 + fp];
        float w0 = rec_w(v0), w1 = rec_w(v1), w2 = rec_w(v2), w3 = rec_w(v3);
        a0 += w0 * blo(s0); a1 += w0 * bhi(s0);
        b0 += w1 * blo(s1); b1 += w1 * bhi(s1);
        a0 += w2 * blo(s2); a1 += w2 * bhi(s2);
        b0 += w3 * blo(s3); b1 += w3 * bhi(s3);
    }
    for (; i < e; ++i) {
        unsigned v = ed[i];
        unsigned sv = src[rec_r(v) * 32 + fp];
        float w = rec_w(v);
        a0 += w * blo(sv); a1 += w * bhi(sv);
    }
    a0 += b0; a1 += b1;
    float d = dinv[n];
    q[n * 32 + fp] = packbf(d * a0, d * a1);
}

// ---------- dense layers (verbatim round 8) ----------
__global__ __launch_bounds__(256) void dense1b_k(const float* __restrict__ x,
                                                 const bf16* __restrict__ p1,
                                                 const bf16* __restrict__ p2,
                                                 const float* __restrict__ w,
                                                 const float* __restrict__ b,
                                                 const float* __restrict__ dinv,
                                                 bf16* __restrict__ h1s,
                                                 bf16* __restrict__ h1p) {
    __shared__ float sw[3 * IN_F * HID];  // 24 KB
    __shared__ float sx[4][3 * IN_F];
    for (int i = threadIdx.x; i < 3 * IN_F * HID; i += 256) sw[i] = w[i];
    int nb = blockIdx.x * 4;
    for (int k = threadIdx.x; k < 4 * 96; k += 256) {
        int ln = k / 96, j = k % 96;
        int n = nb + ln;
        float v = 0.f;
        if (n < N_NODES) {
            int hop = j >> 5, ii = j & 31;
            if (hop == 0) v = x[n * IN_F + ii];
            else v = b2f((hop == 1 ? p1 : p2)[n * IN_F + ii]);
        }
        sx[ln][j] = v;
    }
    __syncthreads();
    int ln = threadIdx.x >> 6;
    int n = nb + ln;
    if (n >= N_NODES) return;
    int f = threadIdx.x & 63;
    float acc = b[f];
#pragma unroll 8
    for (int j = 0; j < 96; ++j) acc += sx[ln][j] * sw[j * HID + f];
    acc = acc > 0.f ? acc : 0.01f * acc;
    h1s[n * HID + f] = __float2bfloat16(acc * dinv[n]);
    if (n < NUM_APS) h1p[n * HID + f] = __float2bfloat16(acc);
}

__global__ __launch_bounds__(256) void dense2_k(const bf16* __restrict__ h1p,
                                                const bf16* __restrict__ q1,
                                                const bf16* __restrict__ q2,
                                                const float* __restrict__ w,
                                                const float* __restrict__ b,
                                                float* __restrict__ ap) {
    __shared__ float sw[3 * HID * HID];  // 48 KB
    __shared__ float sx[4][3 * HID];
    for (int i = threadIdx.x; i < 3 * HID * HID; i += 256) sw[i] = w[i];
    int nb = blockIdx.x * 4;
    for (int k = threadIdx.x; k < 4 * 192; k += 256) {
        int ln = k / 192, j = k % 192;
        int n = nb + ln;
        float v = 0.f;
        if (n < NUM_APS) {
            int hop = j >> 6, ii = j & 63;
            const bf16* sp = (hop == 0) ? h1p : (hop == 1 ? q1 : q2);
            v = b2f(sp[n * HID + ii]);
        }
        sx[ln][j] = v;
    }
    __syncthreads();
    int ln = threadIdx.x >> 6;
    int n = nb + ln;
    if (n >= NUM_APS) return;
    int f = threadIdx.x & 63;
    float acc = b[f];
#pragma unroll 8
    for (int j = 0; j < 192; ++j) acc += sx[ln][j] * sw[j * HID + f];
    acc = acc > 0.f ? acc : 0.01f * acc;
    ap[n * HID + f] = acc;
}

// two 64->3 heads (verbatim)
__global__ void logits_k(const float* __restrict__ ap,
                         const float* __restrict__ wch, const float* __restrict__ bch,
                         const float* __restrict__ wpw, const float* __restrict__ bpw,
                         float* __restrict__ out) {
    int idx = blockIdx.x * blockDim.x + threadIdx.x;
    if (idx >= NUM_APS * 6) return;
    int n = idx / 6, j = idx % 6;
    const float* w;
    float bb;
    float* o;
    if (j < 3) {
        w = wch + j; bb = bch[j]; o = out + n * 3 + j;
    } else {
        int jj = j - 3;
        w = wpw + jj; bb = bpw[jj]; o = out + NUM_APS * 3 + n * 3 + jj;
    }
    float acc = bb;
    const float* a = ap + n * HID;
#pragma unroll
    for (int i = 0; i < HID; ++i) acc += a[i] * w[i * 3];
    *o = acc;
}

extern "C" void kernel_launch(void* const* d_in, const int* in_sizes, int n_in,
                              void* d_out, int out_size, void* d_ws, size_t ws_size,
                              hipStream_t stream) {
    const float* x   = (const float*)d_in[0];
    const int*   ei  = (const int*)d_in[1];
    const float* ea  = (const float*)d_in[2];
    const float* w1  = (const float*)d_in[3];
    const float* b1  = (const float*)d_in[4];
    const float* w2  = (const float*)d_in[5];
    const float* b2  = (const float*)d_in[6];
    const float* wch = (const float*)d_in[7];
    const float* bch = (const float*)d_in[8];
    const float* wpw = (const float*)d_in[9];
    const float* bpw = (const float*)d_in[10];

    const int E = in_sizes[2];  // 1,600,000
    const int* row  = ei;
    const int* colv = ei + E;

    // ---- workspace layout (4-byte units), ~46.3 MB ----
    float* ws = (float*)d_ws;
    ull*      staging = (ull*)ws;                     // E ull = [0, 3.2M)
    unsigned* ed      = (unsigned*)(ws + 3200000);    // [3.2M, 4.8M)
    int*      binCnt  = (int*)(ws + 4800000);         // 512
    int*      binBase = (int*)(ws + 4800512);         // 512 (needs NB+1)
    int*      binPtr  = (int*)(ws + 4801024);         // 512
    int*      off     = (int*)(ws + 4802048);         // [.., +100000)
    float*    dinv    = ws + 4902048;                 // [.., +100000)
    unsigned* xs      = (unsigned*)(ws + 5002048);    // 1.6M
    unsigned* u1      = xs + 1600000;                 // 1.6M
    unsigned* p1      = (unsigned*)(ws + 8202048);    // 1.6M
    unsigned* p2      = p1 + 1600000;                 // 1.6M
    unsigned* h1s     = xs;                           // overlays xs∪u1 (3.2M)
    unsigned* u3      = p1;                           // overlays p1∪p2 (3.2M)
    bf16*     h1p     = (bf16*)(ws + 11402048);       // 32K units
    bf16*     q1      = (bf16*)(ws + 11434048);       // 32K
    bf16*     q2      = (bf16*)(ws + 11466048);       // 32K
    float*    ap      = ws + 11498048;                // 64K

    const int gridE = (E + EPB - 1) / EPB;  // 391 for E=1.6M

    // ---- binned CSR build (all scattered stores L2-resident) ----
    hipMemsetAsync(binCnt, 0, 512 * sizeof(int), stream);
    hist_k<<<gridE, 256, 0, stream>>>(colv, binCnt, E);
    binscan_k<<<1, 512, 0, stream>>>(binCnt, binBase, binPtr);
    binwrite_k<<<gridE, 256, 0, stream>>>(row, colv, ea, binPtr, staging, E);
    binfin_k<<<NB, 256, 0, stream>>>(staging, binBase, ed, off, dinv);

    // ---- layer 1 ----
    xs_k<<<(N_NODES * IN_F + 255) / 256, 256, 0, stream>>>(x, dinv, (bf16*)xs,
                                                           N_NODES * IN_F);
    gath32_dual_k<<<(N_NODES * 16 + 255) / 256, 256, 0, stream>>>(ed, off, dinv, xs,
                                                                  p1, u1, N_NODES);
    gath32_one_k<<<(N_NODES * 16 + 255) / 256, 256, 0, stream>>>(ed, off, dinv, u1,
                                                                 p2, N_NODES);
    dense1b_k<<<(N_NODES + 3) / 4, 256, 0, stream>>>(x, (bf16*)p1, (bf16*)p2, w1, b1,
                                                     dinv, (bf16*)h1s, h1p);

    // ---- layer 2 ----
    gath64_dual_k<<<(N_NODES * 32 + 255) / 256, 256, 0, stream>>>(ed, off, dinv, h1s,
                                                                  u3, (unsigned*)q1,
                                                                  N_NODES, NUM_APS);
    gath64_one_k<<<(NUM_APS * 32 + 255) / 256, 256, 0, stream>>>(ed, off, dinv, u3,
                                                                 (unsigned*)q2, NUM_APS);
    dense2_k<<<(NUM_APS + 3) / 4, 256, 0, stream>>>(h1p, q1, q2, w2, b2, ap);

    // ---- heads ----
    logits_k<<<(NUM_APS * 6 + 255) / 256, 256, 0, stream>>>(ap, wch, bch, wpw, bpw,
                                                            (float*)d_out);
}